// Round 10
// baseline (751.410 us; speedup 1.0000x reference)
//
#include <hip/hip_runtime.h>

// 2-layer hetero GraphSAGE, fp32 compute, bf16 gather tables, direct-scatter
// slack CSR build, persistent-weight register-tiled combines.
// HARD RULES (accumulated post-mortems):
//  R6/R7: one K-loop (one weight matrix tile) per kernel body — dual-weight
//    loops spill to 256 VGPR + scratch. Fusion via PRE operand, block-range
//    select, or CONCAT-K (stacked weights in ONE LDS tile, one loop).
//  R8: split gathers lower FETCH but not time (latency-bound) — keep fused dual gather.
//  R9 (VERIFIED 73.9-74.3us): gather = one coalesced offset-vector load + __shfl
//    distribution + 8-deep burst of row loads with per-lane masks + ZERO-INIT.
//    The zero-inits are LOAD-LIVENESS ANCHORS (force v0..v7 live together).
//  R10: removing the anchors serializes the burst (74.4 -> 79.6). Gather is
//    memory-request-service + VALU-issue co-limited; load section is frozen.
//  R11 (REVERTED): RUNTIME epilogue flags -> VGPR 248, occupancy 10%, 3x
//    regression. Combine polymorphism must be COMPILE-TIME, identical flags
//    on both sides of a block-range pair. Block-range fusion of distinct
//    cold bodies is safe.
//  R13 (VERIFIED −22us): concat-K layer-2 single pass; pre-gather hoist.
//  R14 (−5us only): label-sorted classifier — hp/hu are L3-resident; reverted.
//  R15 (VERIFIED −10us): histogram+scan DELETED; fixed-slack bucket layout.
//  R16 (neutral): float2/pk_add gather ACC kept; partCast fusion revealed the
//    counting sort ITSELF as the bottleneck (80us top dispatch, occ 29%,
//    1.24M LDS bank conflicts, 10-edge scattered segment writes).
//  R17 (CRASHED): direct-scatter slack CSR — correct design, but the counter
//    memset spanned two SEPARATE 256B-aligned allocations whose gap left 48
//    cntU counters uninitialized -> negative garbage passed the slack guard ->
//    OOB write. RULE: memset must cover the actual aligned span; allocate
//    jointly-cleared arrays as ONE block.
//  R18: fix = cntP/cntU in one allocation (cntU = cntP + NP); design unchanged.

using u16 = unsigned short;
using u32 = unsigned int;

__device__ __forceinline__ u16 bf16r(float f) {            // round-to-nearest-even
    u32 b = __float_as_uint(f);
    b += 0x7fffu + ((b >> 16) & 1u);
    return (u16)(b >> 16);
}
__device__ __forceinline__ float2 bfup(u32 u) {            // (lo,hi) bf16 -> f32 pair
    return make_float2(__uint_as_float(u << 16), __uint_as_float(u & 0xffff0000u));
}

#define FMA_ROW(ACC, O, W4) \
    ACC[0] += (O) * (W4).x; ACC[1] += (O) * (W4).y; \
    ACC[2] += (O) * (W4).z; ACC[3] += (O) * (W4).w;

// ---- fused build: 4 block ranges (ctile x2 first = longest jobs, then
// scatter, then cast). ctile uses the static 49.7KB LDS; scatter/cast ignore it.
// [0,g128) ctile side0: bfB = bf16(xp@Wrl), fp32 -> sinkF (dead);
// [g128,2*g128) ctile side1: h_p = xp@Wbr, bf16 -> sinkB (dead);
// [sStart,cStart) direct-scatter CSR build (both directions per edge);
// [cStart,..) cast x_user -> bf16.
__global__ __launch_bounds__(256) void k_buildAll(
    const int* __restrict__ esrc, const int* __restrict__ edst, int E,
    int* __restrict__ cntP, int* __restrict__ nbrP, int SLPn,
    int* __restrict__ cntU, int* __restrict__ nbrU, int SLUn,
    int g128, int sStart, int cStart, int NPc,
    const float* __restrict__ xp, const float* __restrict__ Wrl,
    const float* __restrict__ Wbr, u16* __restrict__ bfB,
    float* __restrict__ h_p, float* __restrict__ sinkF, u16* __restrict__ sinkB,
    const float* __restrict__ xc, u16* __restrict__ yc, int n8) {
    __shared__ __align__(16) char smem[49664];
    int tid = threadIdx.x;
    int bix = blockIdx.x;
    if (bix < 2 * g128) {                        // ---- ctile ranges ----
        float* Ws = (float*)smem;                // 128*64 floats = 32768 B
        float* op = (float*)(smem + 32768);      // 32*132 floats = 16896 B
        const float* W; float* h; u16* hbf;
        int bid;
        if (bix < g128) { W = Wrl; h = sinkF; hbf = bfB;   bid = bix; }
        else            { W = Wbr; h = h_p;   hbf = sinkB; bid = bix - g128; }
        for (int i = tid; i < 128 * 16; i += 256)
            ((float4*)Ws)[i] = ((const float4*)W)[i];
        const int c4 = (tid & 15) * 4;
        const int rb = (tid >> 4) * 2;
        const int ntiles = (NPc + 31) / 32;
        for (int tile = bid; tile < ntiles; tile += g128) {
            const int row0 = tile * 32;
            __syncthreads();
            for (int i = tid; i < 32 * 32; i += 256) {
                int r = i >> 5, k4 = (i & 31) * 4;
                int row = row0 + r;
                float4 v = make_float4(0.f, 0.f, 0.f, 0.f);
                if (row < NPc) v = *(const float4*)(xp + (size_t)row * 128 + k4);
                *(float4*)(op + r * 132 + k4) = v;
            }
            __syncthreads();
            float acc[2][4];
#pragma unroll
            for (int i = 0; i < 2; ++i) {
                acc[i][0] = 0.f; acc[i][1] = 0.f; acc[i][2] = 0.f; acc[i][3] = 0.f;
            }
            for (int kk = 0; kk < 128; kk += 4) {
                float4 w0 = *(const float4*)(Ws + (kk + 0) * 64 + c4);
                float4 w1 = *(const float4*)(Ws + (kk + 1) * 64 + c4);
                float4 w2 = *(const float4*)(Ws + (kk + 2) * 64 + c4);
                float4 w3 = *(const float4*)(Ws + (kk + 3) * 64 + c4);
#pragma unroll
                for (int i = 0; i < 2; ++i) {
                    float4 o = *(const float4*)(op + (rb + i) * 132 + kk);
                    FMA_ROW(acc[i], o.x, w0);
                    FMA_ROW(acc[i], o.y, w1);
                    FMA_ROW(acc[i], o.z, w2);
                    FMA_ROW(acc[i], o.w, w3);
                }
            }
#pragma unroll
            for (int i = 0; i < 2; ++i) {
                int row = row0 + rb + i;
                if (row >= NPc) continue;
                float v0 = acc[i][0], v1 = acc[i][1], v2 = acc[i][2], v3 = acc[i][3];
                *(float4*)(h + (size_t)row * 64 + c4) = make_float4(v0, v1, v2, v3);
                uint2 o;
                o.x = (u32)bf16r(v0) | ((u32)bf16r(v1) << 16);
                o.y = (u32)bf16r(v2) | ((u32)bf16r(v3) << 16);
                *(uint2*)(hbf + (size_t)row * 64 + c4) = o;
            }
        }
        return;
    }
    if (bix < cStart) {                          // ---- scatter range ----
        int i = (bix - sStart) * 256 + tid;
        int E4 = E >> 2;
#define SCAT(U, P) { \
        int pp = atomicAdd(&cntP[P], 1); \
        if (pp < SLPn) nbrP[(size_t)(P) * SLPn + pp] = (U) << 7; \
        int pu = atomicAdd(&cntU[U], 1); \
        if (pu < SLUn) nbrU[(size_t)(U) * SLUn + pu] = (P) << 7; }
        if (i < E4) {
            int4 s = ((const int4*)esrc)[i];
            int4 d = ((const int4*)edst)[i];
            SCAT(s.x, d.x) SCAT(s.y, d.y) SCAT(s.z, d.z) SCAT(s.w, d.w)
        }
        if (bix == sStart && tid < (E & 3)) {
            int e = E4 * 4 + tid;
            SCAT(esrc[e], edst[e])
        }
#undef SCAT
        return;
    }
    // ---- cast range ----
    int i = (bix - cStart) * 256 + tid;
    if (i < n8) {
        const float4* x4 = (const float4*)xc;
        float4 a = x4[i * 2], b = x4[i * 2 + 1];
        uint4 o;
        o.x = (u32)bf16r(a.x) | ((u32)bf16r(a.y) << 16);
        o.y = (u32)bf16r(a.z) | ((u32)bf16r(a.w) << 16);
        o.z = (u32)bf16r(b.x) | ((u32)bf16r(b.y) << 16);
        o.w = (u32)bf16r(b.z) | ((u32)bf16r(b.w) << 16);
        ((uint4*)yc)[i] = o;
    }
}

// R16: float2 accumulators — the two adds per dword fuse to v_pk_add_f32.
#define ACC8(A01,A23,A45,A67,V) \
    A01 += bfup((V).x); A23 += bfup((V).y); A45 += bfup((V).z); A67 += bfup((V).w);

// ------- fused dual gather-mean: nodes [0,NA) CSR A, [NA,NA+NB) CSR B -------
// wave per node; 8 lanes per bf16 row (uint4). R9 load shape — do not restructure.
// R17: slack CSR — st = n*SL, deg = min(cnt[n], SL) (safety clamp, never hit).
__global__ __launch_bounds__(256) void k_gather2(
    const u16* __restrict__ yA, const int* __restrict__ nbrA,
    const int* __restrict__ cntA, int SLA, float* __restrict__ aggA, int NA,
    const u16* __restrict__ yB, const int* __restrict__ nbrB,
    const int* __restrict__ cntB, int SLB, float* __restrict__ aggB, int NB) {
    int w = (blockIdx.x * 256 + threadIdx.x) >> 6;
    int lane = threadIdx.x & 63;
    if (w >= NA + NB) return;
    const u16* y; const int* nbr; const int* cntp; float* agg; int n, SL;
    if (w < NA) { y = yA; nbr = nbrA; cntp = cntA; agg = aggA; n = w; SL = SLA; }
    else        { y = yB; nbr = nbrB; cntp = cntB; agg = aggB; n = w - NA; SL = SLB; }
    const int q = lane >> 3, t = lane & 7;
    const int d = min(cntp[n], SL);
    const int st = n * SL;
    const char* yb = (const char*)y + t * 16;
    float2 a01 = make_float2(0.f, 0.f), a23 = make_float2(0.f, 0.f);
    float2 a45 = make_float2(0.f, 0.f), a67 = make_float2(0.f, 0.f);
    for (int j = 0; j < d; j += 64) {
        const int cnt = min(d - j, 64);           // wave-uniform
        int offv = 0;
        if (lane < cnt) offv = nbr[st + j + lane];   // one coalesced 256B load
        // distribute + burst-issue all row loads (independent, exec-masked tails)
#define GLD(R) \
        int g##R = __shfl(offv, R * 8 + q, 64); \
        uint4 v##R = make_uint4(0u, 0u, 0u, 0u); \
        if (R * 8 + q < cnt) v##R = *(const uint4*)(yb + g##R);
        GLD(0) GLD(1) GLD(2) GLD(3) GLD(4) GLD(5) GLD(6) GLD(7)
#undef GLD
        // accumulate (rounds beyond cnt are uniform-skipped; masked lanes hold 0)
#define ACCR(R) if (R * 8 < cnt) { ACC8(a01,a23,a45,a67,v##R) }
        ACCR(0) ACCR(1) ACCR(2) ACCR(3) ACCR(4) ACCR(5) ACCR(6) ACCR(7)
#undef ACCR
    }
#pragma unroll
    for (int m = 8; m < 64; m <<= 1) {
        a01.x += __shfl_xor(a01.x, m, 64); a01.y += __shfl_xor(a01.y, m, 64);
        a23.x += __shfl_xor(a23.x, m, 64); a23.y += __shfl_xor(a23.y, m, 64);
        a45.x += __shfl_xor(a45.x, m, 64); a45.y += __shfl_xor(a45.y, m, 64);
        a67.x += __shfl_xor(a67.x, m, 64); a67.y += __shfl_xor(a67.y, m, 64);
    }
    if (q == 0) {
        float dinv = 1.0f / (float)max(d, 1);
        float* dstp = agg + n * 64 + t * 8;
        *(float4*)dstp       = make_float4(a01.x * dinv, a01.y * dinv, a23.x * dinv, a23.y * dinv);
        *(float4*)(dstp + 4) = make_float4(a45.x * dinv, a45.y * dinv, a67.x * dinv, a67.y * dinv);
    }
}

// ======= paired combine: two independent K-dim problems, block-range selected =======
// COMPILE-TIME flags, IDENTICAL for both sides (R11 rule). Single K-loop body.
// h = act((PRE?pre:0) + (BIAS?b:0) + x@W); always STORE; optional RELU + EMIT.
template <int K, bool PRE, bool BIAS, bool RELU, bool EMIT>
__global__ __launch_bounds__(256) void k_ctilePairX(
    const float* __restrict__ pre0, const float* __restrict__ bias0,
    const float* __restrict__ x0, const float* __restrict__ W0,
    float* __restrict__ h0, u16* __restrict__ hbf0, int N0, int g0,
    const float* __restrict__ pre1, const float* __restrict__ bias1,
    const float* __restrict__ x1, const float* __restrict__ W1,
    float* __restrict__ h1, u16* __restrict__ hbf1, int N1) {
    constexpr int ROWS = (K == 64) ? 64 : 32;
    constexpr int RR = ROWS / 16;
    constexpr int STRIDE = K + 4;
    constexpr int KF4 = K / 4;
    __shared__ float Ws[K * 64];
    __shared__ float op[ROWS * STRIDE];
    const float* pre; const float* bias; const float* x; const float* W;
    float* h; u16* hbf;
    int N, bid, gsz;
    if ((int)blockIdx.x < g0) {
        pre = pre0; bias = bias0; x = x0; W = W0; h = h0; hbf = hbf0; N = N0;
        bid = blockIdx.x; gsz = g0;
    } else {
        pre = pre1; bias = bias1; x = x1; W = W1; h = h1; hbf = hbf1; N = N1;
        bid = blockIdx.x - g0; gsz = gridDim.x - g0;
    }
    const int tid = threadIdx.x;
    for (int i = tid; i < K * 16; i += 256)
        ((float4*)Ws)[i] = ((const float4*)W)[i];
    const int c4 = (tid & 15) * 4;
    const int rb = (tid >> 4) * RR;
    float bx_ = 0.f, by_ = 0.f, bz_ = 0.f, bw_ = 0.f;
    if (BIAS) {
        float4 b4 = *(const float4*)(bias + c4);
        bx_ = b4.x; by_ = b4.y; bz_ = b4.z; bw_ = b4.w;
    }
    const int ntiles = (N + ROWS - 1) / ROWS;
    for (int tile = bid; tile < ntiles; tile += gsz) {
        const int row0 = tile * ROWS;
        __syncthreads();
        for (int i = tid; i < ROWS * KF4; i += 256) {
            int r = i / KF4, k4 = (i % KF4) * 4;
            int row = row0 + r;
            float4 v = make_float4(0.f, 0.f, 0.f, 0.f);
            if (row < N) v = *(const float4*)(x + (size_t)row * K + k4);
            *(float4*)(op + r * STRIDE + k4) = v;
        }
        __syncthreads();
        float acc[RR][4];
#pragma unroll
        for (int i = 0; i < RR; ++i) {
            float px = 0.f, py = 0.f, pz = 0.f, pw = 0.f;
            if (PRE) {
                int row = row0 + rb + i;
                if (row < N) {
                    float4 p = *(const float4*)(pre + row * 64 + c4);
                    px = p.x; py = p.y; pz = p.z; pw = p.w;
                }
            }
            acc[i][0] = bx_ + px; acc[i][1] = by_ + py;
            acc[i][2] = bz_ + pz; acc[i][3] = bw_ + pw;
        }
        for (int kk = 0; kk < K; kk += 4) {
            float4 w0 = *(const float4*)(Ws + (kk + 0) * 64 + c4);
            float4 w1 = *(const float4*)(Ws + (kk + 1) * 64 + c4);
            float4 w2 = *(const float4*)(Ws + (kk + 2) * 64 + c4);
            float4 w3 = *(const float4*)(Ws + (kk + 3) * 64 + c4);
#pragma unroll
            for (int i = 0; i < RR; ++i) {
                float4 o = *(const float4*)(op + (rb + i) * STRIDE + kk);
                FMA_ROW(acc[i], o.x, w0);
                FMA_ROW(acc[i], o.y, w1);
                FMA_ROW(acc[i], o.z, w2);
                FMA_ROW(acc[i], o.w, w3);
            }
        }
#pragma unroll
        for (int i = 0; i < RR; ++i) {
            int row = row0 + rb + i;
            if (row >= N) continue;
            float v0 = acc[i][0], v1 = acc[i][1], v2 = acc[i][2], v3 = acc[i][3];
            if (RELU) {
                v0 = fmaxf(v0, 0.f); v1 = fmaxf(v1, 0.f);
                v2 = fmaxf(v2, 0.f); v3 = fmaxf(v3, 0.f);
            }
            *(float4*)(h + row * 64 + c4) = make_float4(v0, v1, v2, v3);
            if (EMIT) {
                uint2 o;
                o.x = (u32)bf16r(v0) | ((u32)bf16r(v1) << 16);
                o.y = (u32)bf16r(v2) | ((u32)bf16r(v3) << 16);
                *(uint2*)(hbf + row * 64 + c4) = o;
            }
        }
    }
}

// ======= paired CONCAT combine: h = bias + [xa|xb] @ [Wa;Wb], K=128 =======
// ONE K-loop, ONE LDS weight tile (filled from two 64x64 sources).
template <bool BIAS>
__global__ __launch_bounds__(256) void k_ctilePairCat(
    const float* __restrict__ bias0, const float* __restrict__ xa0,
    const float* __restrict__ xb0, const float* __restrict__ Wa0,
    const float* __restrict__ Wb0, float* __restrict__ h0, int N0, int g0,
    const float* __restrict__ bias1, const float* __restrict__ xa1,
    const float* __restrict__ xb1, const float* __restrict__ Wa1,
    const float* __restrict__ Wb1, float* __restrict__ h1, int N1) {
    constexpr int ROWS = 32, RR = 2, STRIDE = 132, KF4 = 32;
    __shared__ float Ws[128 * 64];
    __shared__ float op[ROWS * STRIDE];
    const float* bias; const float* xa; const float* xb;
    const float* Wa; const float* Wb; float* h;
    int N, bid, gsz;
    if ((int)blockIdx.x < g0) {
        bias = bias0; xa = xa0; xb = xb0; Wa = Wa0; Wb = Wb0; h = h0; N = N0;
        bid = blockIdx.x; gsz = g0;
    } else {
        bias = bias1; xa = xa1; xb = xb1; Wa = Wa1; Wb = Wb1; h = h1; N = N1;
        bid = blockIdx.x - g0; gsz = gridDim.x - g0;
    }
    const int tid = threadIdx.x;
    for (int i = tid; i < 64 * 16; i += 256) {
        ((float4*)Ws)[i]           = ((const float4*)Wa)[i];
        ((float4*)Ws)[64 * 16 + i] = ((const float4*)Wb)[i];
    }
    const int c4 = (tid & 15) * 4;
    const int rb = (tid >> 4) * RR;
    float bx_ = 0.f, by_ = 0.f, bz_ = 0.f, bw_ = 0.f;
    if (BIAS) {
        float4 b4 = *(const float4*)(bias + c4);
        bx_ = b4.x; by_ = b4.y; bz_ = b4.z; bw_ = b4.w;
    }
    const int ntiles = (N + ROWS - 1) / ROWS;
    for (int tile = bid; tile < ntiles; tile += gsz) {
        const int row0 = tile * ROWS;
        __syncthreads();
        for (int i = tid; i < ROWS * KF4; i += 256) {
            int r = i >> 5, k4 = (i & 31) * 4;
            int row = row0 + r;
            float4 v = make_float4(0.f, 0.f, 0.f, 0.f);
            if (row < N)
                v = (k4 < 64) ? *(const float4*)(xa + (size_t)row * 64 + k4)
                              : *(const float4*)(xb + (size_t)row * 64 + (k4 - 64));
            *(float4*)(op + r * STRIDE + k4) = v;
        }
        __syncthreads();
        float acc[RR][4];
#pragma unroll
        for (int i = 0; i < RR; ++i) {
            acc[i][0] = bx_; acc[i][1] = by_; acc[i][2] = bz_; acc[i][3] = bw_;
        }
        for (int kk = 0; kk < 128; kk += 4) {
            float4 w0 = *(const float4*)(Ws + (kk + 0) * 64 + c4);
            float4 w1 = *(const float4*)(Ws + (kk + 1) * 64 + c4);
            float4 w2 = *(const float4*)(Ws + (kk + 2) * 64 + c4);
            float4 w3 = *(const float4*)(Ws + (kk + 3) * 64 + c4);
#pragma unroll
            for (int i = 0; i < RR; ++i) {
                float4 o = *(const float4*)(op + (rb + i) * STRIDE + kk);
                FMA_ROW(acc[i], o.x, w0);
                FMA_ROW(acc[i], o.y, w1);
                FMA_ROW(acc[i], o.z, w2);
                FMA_ROW(acc[i], o.w, w3);
            }
        }
#pragma unroll
        for (int i = 0; i < RR; ++i) {
            int row = row0 + rb + i;
            if (row >= N) continue;
            *(float4*)(h + row * 64 + c4) =
                make_float4(acc[i][0], acc[i][1], acc[i][2], acc[i][3]);
        }
    }
}

// ------- out[e] = dot64(hu[lu[e]], hp[lp[e]]); quarter-wave per edge, float4 -------
__global__ __launch_bounds__(256) void k_classify4(const float* __restrict__ hu,
                                                   const float* __restrict__ hp,
                                                   const int* __restrict__ lu,
                                                   const int* __restrict__ lp,
                                                   float* __restrict__ out, int EL) {
    int w = (blockIdx.x * 256 + threadIdx.x) >> 6;
    int lane = threadIdx.x & 63;
    int q = lane >> 4, t = lane & 15;
    int e = w * 4 + q;
    float v = 0.f;
    if (e < EL) {
        int u = lu[e], p = lp[e];
        float4 a = *(const float4*)(hu + (size_t)u * 64 + t * 4);
        float4 b = *(const float4*)(hp + (size_t)p * 64 + t * 4);
        v = a.x * b.x + a.y * b.y + a.z * b.z + a.w * b.w;
    }
#pragma unroll
    for (int m = 1; m < 16; m <<= 1) v += __shfl_xor(v, m, 64);
    if (t == 0 && e < EL) out[e] = v;
}

extern "C" void kernel_launch(void* const* d_in, const int* in_sizes, int n_in,
                              void* d_out, int out_size, void* d_ws, size_t ws_size,
                              hipStream_t stream) {
    const float* x_user    = (const float*)d_in[0];
    const float* x_product = (const float*)d_in[1];
    const float* W1bl = (const float*)d_in[2];
    const float* b1b  = (const float*)d_in[3];
    const float* W1br = (const float*)d_in[4];
    const float* W1rl = (const float*)d_in[5];
    const float* b1r  = (const float*)d_in[6];
    const float* W1rr = (const float*)d_in[7];
    const float* W2bl = (const float*)d_in[8];
    const float* b2b  = (const float*)d_in[9];
    const float* W2br = (const float*)d_in[10];
    const float* W2rl = (const float*)d_in[11];
    const float* b2r  = (const float*)d_in[12];
    const float* W2rr = (const float*)d_in[13];
    const int* esrc = (const int*)d_in[14];
    const int* edst = (const int*)d_in[15];
    const int* lu   = (const int*)d_in[16];
    const int* lp   = (const int*)d_in[17];

    const int NU = in_sizes[0] / 64;
    const int NP = in_sizes[1] / 128;
    const int E  = in_sizes[14];
    const int EL = in_sizes[16];

    // ---- per-node slack: mean*2 + margin (P: 128 @14sigma, U: 64 @9.8sigma) ----
    const int SLPn = 2 * (E / NP) + 48;
    const int SLUn = 2 * (E / NU) + 24;

    // ---- workspace layout ----
    char* ws = (char*)d_ws;
    size_t off = 0;
    auto alloc = [&](size_t bytes) -> void* {
        void* p = ws + off;
        off += (bytes + 255) & ~(size_t)255;
        return p;
    };
    // R18: counters in ONE allocation so a single memset covers them exactly.
    int*   cntP   = (int*)alloc(((size_t)NP + NU) * 4);
    int*   cntU   = cntP + NP;
    int*   nbr_p  = (int*)alloc((size_t)NP * SLPn * 4);
    int*   nbr_u  = (int*)alloc((size_t)NU * SLUn * 4);
    float* aggP   = (float*)alloc((size_t)NP * 64 * 4);
    float* aggU   = (float*)alloc((size_t)NU * 64 * 4);
    u16*   bfA    = (u16*)alloc((size_t)NU * 64 * 2);  // x_user_bf, then h_u_bf
    u16*   bfB    = (u16*)alloc((size_t)NP * 64 * 2);  // y_p1_bf,  then h_p_bf
    float* h_p    = (float*)alloc((size_t)NP * 64 * 4);
    float* h_u    = (float*)alloc((size_t)NU * 64 * 4);
    // pre-gather dead-write sinks (h_u not yet live: fully overwritten later)
    float* sinkF  = h_u;                               // NP*64*4 = 12.8MB
    u16*   sinkB  = (u16*)((char*)h_u + (size_t)NP * 64 * 4);  // 6.4MB more

    const int tP32 = (NP + 31) / 32;
    const int tU32 = (NU + 31) / 32;
    const int tP64 = (NP + 63) / 64, tU64 = (NU + 63) / 64;
    auto cap = [](int t, int c) { return t < c ? t : c; };

    // ---- build: memset counters, then ONE fused launch
    //      (ctile x2 | scatter | cast) ----
    hipMemsetAsync(cntP, 0, ((size_t)NP + NU) * 4, stream);
    const int n8 = NU * 64 / 8;
    const int castBlocks = (n8 + 255) / 256;
    const int sblocks = ((E >> 2) + 255) / 256;
    const int g128 = cap(tP32, 768);
    const int sStart = 2 * g128;
    const int cStart = sStart + sblocks;
    k_buildAll<<<cStart + castBlocks, 256, 0, stream>>>(
        esrc, edst, E,
        cntP, nbr_p, SLPn,
        cntU, nbr_u, SLUn,
        g128, sStart, cStart, NP,
        x_product, W1rl, W1br, bfB, h_p, sinkF, sinkB,
        x_user, bfA, n8);

    // ---- layer 1: fused dual gather, then ONE paired combine ----
    k_gather2<<<(NP + NU + 3) / 4, 256, 0, stream>>>(
        bfA, nbr_p, cntP, SLPn, aggP, NP,
        bfB, nbr_u, cntU, SLUn, aggU, NU);
    // side0: h_p = relu(h_p + b1b + aggP@W1bl), emit bfB
    // side1: h_u = relu(aggU + b1r + x_user@W1rr), emit bfA
    {
        const int gP = cap(tP64, 512), gU = cap(tU64, 1024);
        k_ctilePairX<64, true, true, true, true><<<gP + gU, 256, 0, stream>>>(
            h_p, b1b, aggP, W1bl, h_p, bfB, NP, gP,
            aggU, b1r, x_user, W1rr, h_u, bfA, NU);
    }

    // ---- layer 2: fused dual gather, then ONE concat-K combine ----
    k_gather2<<<(NP + NU + 3) / 4, 256, 0, stream>>>(
        bfA, nbr_p, cntP, SLPn, aggP, NP,
        bfB, nbr_u, cntU, SLUn, aggU, NU);
    // side0: h_p = b2b + [aggP|h_p] @ [W2bl;W2br]
    // side1: h_u = b2r + [aggU|h_u] @ [W2rl;W2rr]
    {
        const int gP = cap(tP32, 512), gU = cap(tU32, 1024);
        k_ctilePairCat<true><<<gP + gU, 256, 0, stream>>>(
            b2b, aggP, h_p, W2bl, W2br, h_p, NP, gP,
            b2r, aggU, h_u, W2rl, W2rr, h_u, NU);
    }

    // ---- classifier ----
    k_classify4<<<((EL + 3) / 4 + 3) / 4, 256, 0, stream>>>(
        h_u, h_p, lu, lp, (float*)d_out, EL);
}